// Round 2
// baseline (153.689 us; speedup 1.0000x reference)
//
#include <hip/hip_runtime.h>
#include <hip/hip_bf16.h>

typedef __attribute__((ext_vector_type(8))) short short8;
typedef __attribute__((ext_vector_type(4))) float floatx4;
typedef __attribute__((ext_vector_type(4))) float f32x4;
typedef unsigned short u16;
typedef unsigned int u32;
typedef __attribute__((ext_vector_type(8))) unsigned short ushort8;

#define LSEQ 1024
#define CHD  128
#define QK_SCALE 0.08838834764831845f  // 1/sqrt(128)

static __device__ __forceinline__ u16 f2b(float f) {
  __hip_bfloat16 h = __float2bfloat16(f);
  return *reinterpret_cast<u16*>(&h);
}
static __device__ __forceinline__ u32 pack2(float a, float b) {
  return (u32)f2b(a) | ((u32)f2b(b) << 16);
}
static __device__ __forceinline__ void gl_lds16(const void* g, void* l) {
  __builtin_amdgcn_global_load_lds((__attribute__((address_space(1))) const void*)g,
                                   (__attribute__((address_space(3))) void*)l, 16, 0, 0);
}

// ---- prep: f32 [bh][128][1024] -> bf16 same layout (outV) + bf16 transposed (outT) ----
__global__ __launch_bounds__(256) void k_prep(const float* __restrict__ in,
                                              u16* __restrict__ outV,
                                              u16* __restrict__ outT) {
  __shared__ u16 tile[32][72];  // rows 144B, 16B-aligned
  int bh = blockIdx.z, c0 = blockIdx.y * 32, s0 = blockIdx.x * 64;
  int tid = threadIdx.x;
  int cl = tid >> 3, sc = tid & 7;
  size_t off = ((size_t)bh * CHD + c0 + cl) * LSEQ + s0 + sc * 8;
  f32x4 a = *(const f32x4*)(in + off);
  f32x4 b = *(const f32x4*)(in + off + 4);
  ushort8 u;
#pragma unroll
  for (int j = 0; j < 4; ++j) { u[j] = f2b(a[j]); u[j + 4] = f2b(b[j]); }
  *(ushort8*)(outV + off) = u;
  *(ushort8*)&tile[cl][sc * 8] = u;
  __syncthreads();
  int sl = tid >> 2, cc = tid & 3;
  ushort8 v;
#pragma unroll
  for (int j = 0; j < 8; ++j) v[j] = tile[cc * 8 + j][sl];
  *(ushort8*)(outT + ((size_t)bh * LSEQ + s0 + sl) * CHD + c0 + cc * 8) = v;
}

// ---- W conv: f32 [512*512] -> bf16 ----
__global__ __launch_bounds__(256) void k_wcvt(const float* __restrict__ w, u16* __restrict__ wb) {
  int base = (blockIdx.x * 256 + threadIdx.x) * 8;
  f32x4 a = *(const f32x4*)(w + base);
  f32x4 b = *(const f32x4*)(w + base + 4);
  ushort8 u;
#pragma unroll
  for (int j = 0; j < 4; ++j) { u[j] = f2b(a[j]); u[j + 4] = f2b(b[j]); }
  *(ushort8*)(wb + base) = u;
}

// ---- flash attention; qT,kT: bf16 [bh][1024][128]; v: bf16 [bh][128][1024];
//      outT: bf16 [bh][1024][128] (transposed write). grid(16,32), 256 thr ----
__global__ __launch_bounds__(256) void k_attn(const u16* __restrict__ qT,
                                              const u16* __restrict__ kT,
                                              const u16* __restrict__ v,
                                              u16* __restrict__ outT) {
  __shared__ char ldsbuf[40960];
  char* ldsK = ldsbuf;            // 16KB: [64 s][256B] row-swizzled
  char* ldsV = ldsbuf + 16384;    // 16KB: [128 c][128B] row-swizzled
  char* ldsP = ldsbuf + 32768;    // 8KB: per-wave [16 t][128B] row-swizzled

  int tt = blockIdx.x, bh = blockIdx.y;
  int tid = threadIdx.x;
  int w = tid >> 6, lane = tid & 63;
  int lo = lane & 15, hi = lane >> 4;
  int t0 = tt * 64 + w * 16;

  const u16* qbase = qT + ((size_t)bh * LSEQ + t0 + lo) * CHD + hi * 8;
  short8 bq[4];
#pragma unroll
  for (int ks = 0; ks < 4; ++ks) bq[ks] = *(const short8*)(qbase + ks * 32);

  floatx4 oacc[8];
#pragma unroll
  for (int i = 0; i < 8; ++i) { oacc[i][0]=0.f; oacc[i][1]=0.f; oacc[i][2]=0.f; oacc[i][3]=0.f; }
  float m_r = -1e30f, l_r = 0.f;

  const char* kTb = (const char*)(kT + (size_t)bh * LSEQ * CHD);  // row s: 256B
  const char* vb  = (const char*)(v  + (size_t)bh * CHD * LSEQ);  // row c: 2048B
  char* pw = ldsP + w * 2048 + lo * 128;
  int sw = (lo & 7) << 4;

  for (int sb = 0; sb < 16; ++sb) {
    // stage K tile: LDS linear dest, pre-swizzled global source
#pragma unroll
    for (int it = 0; it < 4; ++it) {
      int bb = it * 4096 + tid * 16;
      int row = bb >> 8;
      int cb = (bb & 255) ^ ((row & 7) << 4);
      gl_lds16(kTb + (size_t)(sb * 64 + row) * 256 + cb, ldsK + bb);
    }
    // stage V tile [128 c][64 s]
#pragma unroll
    for (int it = 0; it < 4; ++it) {
      int bb = it * 4096 + tid * 16;
      int row = bb >> 7;
      int cb = (bb & 127) ^ ((row & 7) << 4);
      gl_lds16(vb + (size_t)row * 2048 + sb * 128 + cb, ldsV + bb);
    }
    __syncthreads();

    // S^T = K·Q: lane holds S[s-block rows][t = t0+lo]
    float sa[4][4];
#pragma unroll
    for (int ss = 0; ss < 4; ++ss) {
      floatx4 acc; acc[0]=0.f; acc[1]=0.f; acc[2]=0.f; acc[3]=0.f;
      int row = ss * 16 + lo;
#pragma unroll
      for (int ks = 0; ks < 4; ++ks) {
        int cbyte = (ks * 64 + hi * 16) ^ ((row & 7) << 4);
        short8 a = *(const short8*)(ldsK + row * 256 + cbyte);
        acc = __builtin_amdgcn_mfma_f32_16x16x32_bf16(a, bq[ks], acc, 0, 0, 0);
      }
#pragma unroll
      for (int r = 0; r < 4; ++r) sa[ss][r] = acc[r] * QK_SCALE;
    }

    // online softmax over s for this t (in-lane + xor16 + xor32)
    float bm = sa[0][0];
#pragma unroll
    for (int ss = 0; ss < 4; ++ss)
#pragma unroll
      for (int r = 0; r < 4; ++r) bm = fmaxf(bm, sa[ss][r]);
    bm = fmaxf(bm, __shfl_xor(bm, 16));
    bm = fmaxf(bm, __shfl_xor(bm, 32));
    float mn = fmaxf(m_r, bm);
    float corr = __expf(m_r - mn);
    m_r = mn;
    float rs = 0.f;
#pragma unroll
    for (int ss = 0; ss < 4; ++ss)
#pragma unroll
      for (int r = 0; r < 4; ++r) {
        float p = __expf(sa[ss][r] - mn);
        sa[ss][r] = p;
        rs += p;
      }
    rs += __shfl_xor(rs, 16);
    rs += __shfl_xor(rs, 32);
    l_r = l_r * corr + rs;
#pragma unroll
    for (int i = 0; i < 8; ++i) {
      oacc[i][0] *= corr; oacc[i][1] *= corr; oacc[i][2] *= corr; oacc[i][3] *= corr;
    }

    // P tile (bf16) -> per-wave LDS [t=lo][s], row-swizzled
#pragma unroll
    for (int ss = 0; ss < 4; ++ss)
#pragma unroll
      for (int r2 = 0; r2 < 2; ++r2) {
        int scol = ss * 16 + hi * 4 + r2 * 2;
        *(u32*)(pw + ((scol * 2) ^ sw)) = pack2(sa[ss][r2 * 2], sa[ss][r2 * 2 + 1]);
      }
    asm volatile("" ::: "memory");  // keep P write -> P read ordered (TBAA hazard)

    // PV: O[c][t] += sum_s V[c][s] P[t][s]
#pragma unroll
    for (int mt = 0; mt < 8; ++mt) {
      int crow = mt * 16 + lo;
      const char* va = ldsV + crow * 128;
      int vsw = (crow & 7) << 4;
#pragma unroll
      for (int k2 = 0; k2 < 2; ++k2) {
        short8 a = *(const short8*)(va + ((k2 * 64 + hi * 16) ^ vsw));
        short8 b = *(const short8*)(pw + ((k2 * 64 + hi * 16) ^ sw));
        oacc[mt] = __builtin_amdgcn_mfma_f32_16x16x32_bf16(a, b, oacc[mt], 0, 0, 0);
      }
    }
    __syncthreads();
  }

  // epilogue: transpose O via per-wave swizzled LDS tile, write outT rows coalesced
  float inv = 1.0f / l_r;
  char* ot = ldsbuf + w * 4096;  // [16 t][256B c], safe: all staging reads done
#pragma unroll
  for (int mt = 0; mt < 8; ++mt)
#pragma unroll
    for (int r2 = 0; r2 < 2; ++r2) {
      int cb = (mt * 32 + hi * 8 + r2 * 4) ^ ((lo & 7) << 4);
      *(u32*)(ot + lo * 256 + cb) = pack2(oacc[mt][r2 * 2] * inv, oacc[mt][r2 * 2 + 1] * inv);
    }
  asm volatile("" ::: "memory");
  u16* orow = outT + ((size_t)bh * LSEQ + t0 + lo) * CHD;
#pragma unroll
  for (int it = 0; it < 4; ++it) {
    int cb = (it * 64 + hi * 16) ^ ((lo & 7) << 4);
    ushort8 d = *(const ushort8*)(ot + lo * 256 + cb);
    *(ushort8*)(orow + it * 32 + hi * 8) = d;
  }
}

// ---- proj: x[b,o,l] = sum_c W[o,c]*eT[b,l,c] + bias; x f32 + channel stats ----
__global__ __launch_bounds__(256) void k_proj(const u16* __restrict__ Wm,    // bf16 [512][512]
                                              const u16* __restrict__ eT,    // bf16 [bh][1024][128]
                                              const float* __restrict__ bias,
                                              float* __restrict__ x,         // f32 [8][512][1024]
                                              float* __restrict__ chsum,
                                              float* __restrict__ chsq) {
  int lt = blockIdx.x, ot = blockIdx.y, b = blockIdx.z;
  int tid = threadIdx.x, w = tid >> 6, lane = tid & 63, lo = lane & 15, hi = lane >> 4;
  int o0 = ot * 64 + w * 16;
  int l0 = lt * 64;
  floatx4 acc[4];
#pragma unroll
  for (int i = 0; i < 4; ++i) { acc[i][0]=0.f; acc[i][1]=0.f; acc[i][2]=0.f; acc[i][3]=0.f; }
  const u16* wrow = Wm + (size_t)(o0 + lo) * 512 + hi * 8;
#pragma unroll
  for (int ks = 0; ks < 16; ++ks) {
    short8 aw = *(const short8*)(wrow + ks * 32);
    int h = ks >> 2, kl = (ks & 3) * 32;
    const u16* bbase = eT + ((size_t)(b * 4 + h) * LSEQ + l0 + lo) * CHD + kl + hi * 8;
#pragma unroll
    for (int ns = 0; ns < 4; ++ns) {
      short8 bb = *(const short8*)(bbase + (size_t)ns * 16 * CHD);
      acc[ns] = __builtin_amdgcn_mfma_f32_16x16x32_bf16(aw, bb, acc[ns], 0, 0, 0);
    }
  }
  float s_r[4] = {0.f, 0.f, 0.f, 0.f}, q_r[4] = {0.f, 0.f, 0.f, 0.f};
#pragma unroll
  for (int r = 0; r < 4; ++r) {
    int o = o0 + hi * 4 + r;
    float bv = bias[o];
#pragma unroll
    for (int ns = 0; ns < 4; ++ns) {
      float xv = acc[ns][r] + bv;
      x[((size_t)b * 512 + o) * LSEQ + l0 + ns * 16 + lo] = xv;
      s_r[r] += xv;
      q_r[r] += xv * xv;
    }
  }
#pragma unroll
  for (int r = 0; r < 4; ++r) {
    float s = s_r[r], q = q_r[r];
#pragma unroll
    for (int d = 1; d < 16; d <<= 1) { s += __shfl_xor(s, d); q += __shfl_xor(q, d); }
    if (lo == 0) {
      atomicAdd(&chsum[o0 + hi * 4 + r], s);
      atomicAdd(&chsq[o0 + hi * 4 + r], q);
    }
  }
}

// ---- BN stats -> scale/shift ----
__global__ void k_stats(const float* __restrict__ chsum, const float* __restrict__ chsq,
                        const float* __restrict__ gamma, const float* __restrict__ beta,
                        float* __restrict__ scale, float* __restrict__ shift) {
  int ch = blockIdx.x * 256 + threadIdx.x;
  if (ch < 512) {
    const float invn = 1.0f / 8192.0f;
    float mean = chsum[ch] * invn;
    float var = chsq[ch] * invn - mean * mean;
    float rstd = rsqrtf(var + 1e-5f);
    float g = gamma[ch] * rstd;
    scale[ch] = g;
    shift[ch] = beta[ch] - mean * g;
  }
}

// ---- BN apply + swish: f32 in, f32 out ----
__global__ __launch_bounds__(256) void k_final(const float* __restrict__ x,
                                               const float* __restrict__ scale,
                                               const float* __restrict__ shift,
                                               float* __restrict__ out) {
  int idx = blockIdx.x * 256 + threadIdx.x;
  int base = idx * 4;
  int ch = (base >> 10) & 511;
  float sc = scale[ch], sh = shift[ch];
  f32x4 vx = *(const f32x4*)(x + base);
  f32x4 o;
#pragma unroll
  for (int j = 0; j < 4; ++j) {
    float xn = vx[j] * sc + sh;
    float sg = 1.0f / (1.0f + __expf(-xn));
    o[j] = xn * sg;
  }
  *(f32x4*)(out + base) = o;
}

extern "C" void kernel_launch(void* const* d_in, const int* in_sizes, int n_in,
                              void* d_out, int out_size, void* d_ws, size_t ws_size,
                              hipStream_t stream) {
  const float* c     = (const float*)d_in[0];
  const float* e     = (const float*)d_in[1];
  const float* Wf    = (const float*)d_in[2];
  const float* bias  = (const float*)d_in[3];
  const float* gamma = (const float*)d_in[4];
  const float* beta  = (const float*)d_in[5];
  float* outp = (float*)d_out;

  char* ws = (char*)d_ws;
  const size_t TB = (size_t)32 * 1024 * 128 * 2;  // 8.39MB bf16 [bh][*][*] slot
  u16* eT  = (u16*)(ws);                 // S0: eT
  u16* cT  = (u16*)(ws + TB);            // S1: cT, later _eT
  u16* cV  = (u16*)(ws + 2 * TB);        // S2: cV; S2+S3 later x (f32, 16.8MB)
  u16* eV  = (u16*)(ws + 3 * TB);        // S3: eV
  u16* cT2 = (u16*)(ws + 4 * TB);        // S4: _cT
  u16* Wbf = (u16*)(ws + 5 * TB);        // 512KB
  float* chsum = (float*)(ws + 5 * TB + (1 << 20));
  float* chsq  = chsum + 512;
  float* scale = chsq + 512;
  float* shift = scale + 512;
  float* x     = (float*)(ws + 2 * TB);

  dim3 tb(256);
  dim3 pgrid(16, 4, 32);
  dim3 agrid(16, 32);

  k_wcvt<<<dim3(128), tb, 0, stream>>>(Wf, Wbf);
  k_prep<<<pgrid, tb, 0, stream>>>(c, cV, cT);
  k_prep<<<pgrid, tb, 0, stream>>>(e, eV, eT);
  k_attn<<<agrid, tb, 0, stream>>>(eT, cT, cV, cT2);   // _cT = attn(e,c,c)^T
  k_attn<<<agrid, tb, 0, stream>>>(cT2, eT, eV, cT);   // _eT = attn(_c,e,e)^T
  hipMemsetAsync(chsum, 0, 2 * 512 * sizeof(float), stream);
  k_proj<<<dim3(16, 8, 8), tb, 0, stream>>>(Wbf, cT, bias, x, chsum, chsq);
  k_stats<<<dim3(2), tb, 0, stream>>>(chsum, chsq, gamma, beta, scale, shift);
  k_final<<<dim3(4096), tb, 0, stream>>>(x, scale, shift, outp);
}

// Round 3
// 118.485 us; speedup vs baseline: 1.2971x; 1.2971x over previous
//
#include <hip/hip_runtime.h>
#include <hip/hip_bf16.h>

typedef __attribute__((ext_vector_type(8))) short short8;
typedef __attribute__((ext_vector_type(4))) float floatx4;
typedef __attribute__((ext_vector_type(4))) float f32x4;
typedef unsigned short u16;
typedef unsigned int u32;
typedef __attribute__((ext_vector_type(8))) unsigned short ushort8;

#define LSEQ 1024
#define CHD  128
#define QK_SCALE 0.08838834764831845f  // 1/sqrt(sqrt(128))^2 per-side; product = 1/sqrt(128)

static __device__ __forceinline__ u16 f2b(float f) {
  __hip_bfloat16 h = __float2bfloat16(f);
  return *reinterpret_cast<u16*>(&h);
}
static __device__ __forceinline__ u32 pack2(float a, float b) {
  return (u32)f2b(a) | ((u32)f2b(b) << 16);
}
static __device__ __forceinline__ void gl_lds16(const void* g, void* l) {
  __builtin_amdgcn_global_load_lds((__attribute__((address_space(1))) const void*)g,
                                   (__attribute__((address_space(3))) void*)l, 16, 0, 0);
}

// ---- prep: f32 [bh][128][1024] -> bf16 same layout (outV) + bf16 transposed (outT) ----
__global__ __launch_bounds__(256) void k_prep(const float* __restrict__ in,
                                              u16* __restrict__ outV,
                                              u16* __restrict__ outT) {
  __shared__ u16 tile[32][72];
  int bh = blockIdx.z, c0 = blockIdx.y * 32, s0 = blockIdx.x * 64;
  int tid = threadIdx.x;
  int cl = tid >> 3, sc = tid & 7;
  size_t off = ((size_t)bh * CHD + c0 + cl) * LSEQ + s0 + sc * 8;
  f32x4 a = *(const f32x4*)(in + off);
  f32x4 b = *(const f32x4*)(in + off + 4);
  ushort8 u;
#pragma unroll
  for (int j = 0; j < 4; ++j) { u[j] = f2b(a[j]); u[j + 4] = f2b(b[j]); }
  *(ushort8*)(outV + off) = u;
  *(ushort8*)&tile[cl][sc * 8] = u;
  __syncthreads();
  int sl = tid >> 2, cc = tid & 3;
  ushort8 v;
#pragma unroll
  for (int j = 0; j < 8; ++j) v[j] = tile[cc * 8 + j][sl];
  *(ushort8*)(outT + ((size_t)bh * LSEQ + s0 + sl) * CHD + c0 + cc * 8) = v;
}

// ---- W conv: f32 [512*512] -> bf16 ----
__global__ __launch_bounds__(256) void k_wcvt(const float* __restrict__ w, u16* __restrict__ wb) {
  int base = (blockIdx.x * 256 + threadIdx.x) * 8;
  f32x4 a = *(const f32x4*)(w + base);
  f32x4 b = *(const f32x4*)(w + base + 4);
  ushort8 u;
#pragma unroll
  for (int j = 0; j < 4; ++j) { u[j] = f2b(a[j]); u[j + 4] = f2b(b[j]); }
  *(ushort8*)(wb + base) = u;
}

// ---- flash attention, 8 waves, t-tile 128, double-buffered 2-phase pipeline ----
// qT,kT: bf16 [bh][1024][128]; v: bf16 [bh][128][1024]; outT: bf16 [bh][1024][128].
// grid(32 bh, 8 tt) -> linear-wg%8 groups a bh-cluster per XCD (K/V 2MB/XCD L2-fit).
__global__ __launch_bounds__(512) void k_attn(const u16* __restrict__ qT,
                                              const u16* __restrict__ kT,
                                              const u16* __restrict__ v,
                                              u16* __restrict__ outT) {
  __shared__ char ldsbuf[81920];  // K dbuf 2x16KB | V dbuf 2x16KB | P 8x2KB

  int bh = blockIdx.x, tt = blockIdx.y;
  int tid = threadIdx.x;
  int w = tid >> 6, lane = tid & 63;
  int lo = lane & 15, hi = lane >> 4;
  int t0 = tt * 128 + w * 16;

  const char* kTb = (const char*)(kT + (size_t)bh * LSEQ * CHD);  // row s: 256B
  const char* vb  = (const char*)(v  + (size_t)bh * CHD * LSEQ);  // row c: 2048B

  const u16* qbase = qT + ((size_t)bh * LSEQ + t0 + lo) * CHD + hi * 8;
  short8 bq[4];
#pragma unroll
  for (int ks = 0; ks < 4; ++ks) bq[ks] = *(const short8*)(qbase + ks * 32);

  floatx4 oacc[8];
#pragma unroll
  for (int i = 0; i < 8; ++i) { oacc[i][0]=0.f; oacc[i][1]=0.f; oacc[i][2]=0.f; oacc[i][3]=0.f; }
  float m_r = -1e30f, l_r = 0.f;

  char* pw = ldsbuf + 65536 + w * 2048 + lo * 128;
  int sw = (lo & 7) << 4;

  auto stageK = [&](int buf, int sb) {
    char* dst = ldsbuf + buf * 16384;
#pragma unroll
    for (int it = 0; it < 2; ++it) {
      int bb = it * 8192 + tid * 16;
      int row = bb >> 8;
      int cb = (bb & 255) ^ ((row & 7) << 4);
      gl_lds16(kTb + (size_t)(sb * 64 + row) * 256 + cb, dst + bb);
    }
  };
  auto stageV = [&](int buf, int sb) {
    char* dst = ldsbuf + 32768 + buf * 16384;
#pragma unroll
    for (int it = 0; it < 2; ++it) {
      int bb = it * 8192 + tid * 16;
      int row = bb >> 7;
      int cb = (bb & 127) ^ ((row & 7) << 4);
      gl_lds16(vb + (size_t)row * 2048 + sb * 128 + cb, dst + bb);
    }
  };

  stageK(0, 0); stageV(0, 0);
  __syncthreads();
  int cur = 0;

  for (int sb = 0; sb < 16; ++sb) {
    if (sb < 15) { stageK(cur ^ 1, sb + 1); stageV(cur ^ 1, sb + 1); }
    const char* ldsK = ldsbuf + cur * 16384;
    const char* ldsV = ldsbuf + 32768 + cur * 16384;

    // S^T = K.Q: lane holds S[s rows][t = t0+lo]
    float sa[4][4];
#pragma unroll
    for (int ss = 0; ss < 4; ++ss) {
      floatx4 acc; acc[0]=0.f; acc[1]=0.f; acc[2]=0.f; acc[3]=0.f;
      int row = ss * 16 + lo;
#pragma unroll
      for (int ks = 0; ks < 4; ++ks) {
        int cbyte = (ks * 64 + hi * 16) ^ ((row & 7) << 4);
        short8 a = *(const short8*)(ldsK + row * 256 + cbyte);
        acc = __builtin_amdgcn_mfma_f32_16x16x32_bf16(a, bq[ks], acc, 0, 0, 0);
      }
#pragma unroll
      for (int r = 0; r < 4; ++r) sa[ss][r] = acc[r] * QK_SCALE;
    }

    // online softmax over s for this t
    float bm = sa[0][0];
#pragma unroll
    for (int ss = 0; ss < 4; ++ss)
#pragma unroll
      for (int r = 0; r < 4; ++r) bm = fmaxf(bm, sa[ss][r]);
    bm = fmaxf(bm, __shfl_xor(bm, 16));
    bm = fmaxf(bm, __shfl_xor(bm, 32));
    float mn = fmaxf(m_r, bm);
    float corr = __expf(m_r - mn);
    m_r = mn;
    float rs = 0.f;
#pragma unroll
    for (int ss = 0; ss < 4; ++ss)
#pragma unroll
      for (int r = 0; r < 4; ++r) {
        float p = __expf(sa[ss][r] - mn);
        sa[ss][r] = p;
        rs += p;
      }
    rs += __shfl_xor(rs, 16);
    rs += __shfl_xor(rs, 32);
    l_r = l_r * corr + rs;
#pragma unroll
    for (int i = 0; i < 8; ++i) {
      oacc[i][0] *= corr; oacc[i][1] *= corr; oacc[i][2] *= corr; oacc[i][3] *= corr;
    }

    // P tile (bf16) -> per-wave LDS [t=lo][s], row-swizzled
#pragma unroll
    for (int ss = 0; ss < 4; ++ss)
#pragma unroll
      for (int r2 = 0; r2 < 2; ++r2) {
        int scol = ss * 16 + hi * 4 + r2 * 2;
        *(u32*)(pw + ((scol * 2) ^ sw)) = pack2(sa[ss][r2 * 2], sa[ss][r2 * 2 + 1]);
      }
    asm volatile("" ::: "memory");  // order P write -> P read (TBAA hazard)

    // PV: O[c][t] += sum_s V[c][s] P[t][s]
#pragma unroll
    for (int mt = 0; mt < 8; ++mt) {
      int crow = mt * 16 + lo;
      const char* va = ldsV + crow * 128;
      int vsw = (crow & 7) << 4;
#pragma unroll
      for (int k2 = 0; k2 < 2; ++k2) {
        short8 a = *(const short8*)(va + ((k2 * 64 + hi * 16) ^ vsw));
        short8 b = *(const short8*)(pw + ((k2 * 64 + hi * 16) ^ sw));
        oacc[mt] = __builtin_amdgcn_mfma_f32_16x16x32_bf16(a, b, oacc[mt], 0, 0, 0);
      }
    }
    __syncthreads();
    cur ^= 1;
  }

  // epilogue: transpose O via per-wave swizzled LDS tile, coalesced outT rows
  float inv = 1.0f / l_r;
  char* ot = ldsbuf + w * 4096;  // 8 waves x 4KB inside K dbuf (all K reads done)
#pragma unroll
  for (int mt = 0; mt < 8; ++mt)
#pragma unroll
    for (int r2 = 0; r2 < 2; ++r2) {
      int cb = (mt * 32 + hi * 8 + r2 * 4) ^ ((lo & 7) << 4);
      *(u32*)(ot + lo * 256 + cb) = pack2(oacc[mt][r2 * 2] * inv, oacc[mt][r2 * 2 + 1] * inv);
    }
  asm volatile("" ::: "memory");
  u16* orow = outT + ((size_t)bh * LSEQ + t0 + lo) * CHD;
#pragma unroll
  for (int it = 0; it < 4; ++it) {
    int cb = (it * 64 + hi * 16) ^ ((lo & 7) << 4);
    ushort8 d = *(const ushort8*)(ot + lo * 256 + cb);
    *(ushort8*)(orow + it * 32 + hi * 8) = d;
  }
}

// ---- proj GEMM 512(o) x 8192(b*l) x 512(c): 128x128 tile, BK=64, dbuf 2-phase ----
// x[b,o,l] = sum_c W[o,c]*eT[(b*4+c/128)*1024+l][c%128] + bias[o]; f32 x + channel stats
__global__ __launch_bounds__(256) void k_proj(const u16* __restrict__ Wm,    // bf16 [512][512]
                                              const u16* __restrict__ eT,    // bf16 [32][1024][128]
                                              const float* __restrict__ bias,
                                              float* __restrict__ x,         // f32 [8][512][1024]
                                              float* __restrict__ chsum,
                                              float* __restrict__ chsq) {
  __shared__ char lds[65536];  // A dbuf 2x16KB | B dbuf 2x16KB
  int lt = blockIdx.x, ot = blockIdx.y;
  int b = lt >> 3;
  int l0b = (lt & 7) * 128;
  int o0 = ot * 128;
  int tid = threadIdx.x, w = tid >> 6, lane = tid & 63, lo = lane & 15, hi = lane >> 4;
  int wm = w >> 1, wn = w & 1;
  const char* Wb = (const char*)Wm;
  const char* eTb = (const char*)eT;

  auto stageA = [&](int buf, int kb) {
    char* dst = lds + buf * 16384;
#pragma unroll
    for (int it = 0; it < 4; ++it) {
      int bb = it * 4096 + tid * 16;
      int row = bb >> 7;
      int cb = (bb & 127) ^ ((row & 7) << 4);
      gl_lds16(Wb + (size_t)(o0 + row) * 1024 + kb * 128 + cb, dst + bb);
    }
  };
  auto stageB = [&](int buf, int kb) {
    char* dst = lds + 32768 + buf * 16384;
    int page = b * 4 + (kb >> 1);
    int choff = (kb & 1) * 128;
#pragma unroll
    for (int it = 0; it < 4; ++it) {
      int bb = it * 4096 + tid * 16;
      int row = bb >> 7;
      int cb = (bb & 127) ^ ((row & 7) << 4);
      gl_lds16(eTb + ((size_t)page * 1024 + l0b + row) * 256 + choff + cb, dst + bb);
    }
  };

  floatx4 acc[4][4];
#pragma unroll
  for (int i = 0; i < 4; ++i)
#pragma unroll
    for (int j = 0; j < 4; ++j) { acc[i][j][0]=0.f; acc[i][j][1]=0.f; acc[i][j][2]=0.f; acc[i][j][3]=0.f; }

  stageA(0, 0); stageB(0, 0);
  __syncthreads();
  int cur = 0;

  for (int kb = 0; kb < 8; ++kb) {
    if (kb < 7) { stageA(cur ^ 1, kb + 1); stageB(cur ^ 1, kb + 1); }
    const char* A = lds + cur * 16384;
    const char* B = lds + 32768 + cur * 16384;
#pragma unroll
    for (int kk = 0; kk < 2; ++kk) {
      short8 af[4], bf[4];
#pragma unroll
      for (int mi = 0; mi < 4; ++mi) {
        int row = wm * 64 + mi * 16 + lo;
        af[mi] = *(const short8*)(A + row * 128 + ((kk * 64 + hi * 16) ^ ((row & 7) << 4)));
      }
#pragma unroll
      for (int ni = 0; ni < 4; ++ni) {
        int row = wn * 64 + ni * 16 + lo;
        bf[ni] = *(const short8*)(B + row * 128 + ((kk * 64 + hi * 16) ^ ((row & 7) << 4)));
      }
#pragma unroll
      for (int mi = 0; mi < 4; ++mi)
#pragma unroll
        for (int ni = 0; ni < 4; ++ni)
          acc[mi][ni] = __builtin_amdgcn_mfma_f32_16x16x32_bf16(af[mi], bf[ni], acc[mi][ni], 0, 0, 0);
    }
    __syncthreads();
    cur ^= 1;
  }

  // epilogue: bias + x write (f32) + per-channel partial stats
#pragma unroll
  for (int mi = 0; mi < 4; ++mi) {
#pragma unroll
    for (int r = 0; r < 4; ++r) {
      int o = o0 + wm * 64 + mi * 16 + hi * 4 + r;
      float bv = bias[o];
      float s = 0.f, q = 0.f;
#pragma unroll
      for (int ni = 0; ni < 4; ++ni) {
        float xv = acc[mi][ni][r] + bv;
        x[((size_t)b * 512 + o) * LSEQ + l0b + wn * 64 + ni * 16 + lo] = xv;
        s += xv; q += xv * xv;
      }
#pragma unroll
      for (int d = 1; d < 16; d <<= 1) { s += __shfl_xor(s, d); q += __shfl_xor(q, d); }
      if (lo == 0) {
        atomicAdd(&chsum[o], s);
        atomicAdd(&chsq[o], q);
      }
    }
  }
}

// ---- BN stats -> scale/shift ----
__global__ void k_stats(const float* __restrict__ chsum, const float* __restrict__ chsq,
                        const float* __restrict__ gamma, const float* __restrict__ beta,
                        float* __restrict__ scale, float* __restrict__ shift) {
  int ch = blockIdx.x * 256 + threadIdx.x;
  if (ch < 512) {
    const float invn = 1.0f / 8192.0f;
    float mean = chsum[ch] * invn;
    float var = chsq[ch] * invn - mean * mean;
    float rstd = rsqrtf(var + 1e-5f);
    float g = gamma[ch] * rstd;
    scale[ch] = g;
    shift[ch] = beta[ch] - mean * g;
  }
}

// ---- BN apply + swish: f32 in, f32 out ----
__global__ __launch_bounds__(256) void k_final(const float* __restrict__ x,
                                               const float* __restrict__ scale,
                                               const float* __restrict__ shift,
                                               float* __restrict__ out) {
  int idx = blockIdx.x * 256 + threadIdx.x;
  int base = idx * 4;
  int ch = (base >> 10) & 511;
  float sc = scale[ch], sh = shift[ch];
  f32x4 vx = *(const f32x4*)(x + base);
  f32x4 o;
#pragma unroll
  for (int j = 0; j < 4; ++j) {
    float xn = vx[j] * sc + sh;
    float sg = 1.0f / (1.0f + __expf(-xn));
    o[j] = xn * sg;
  }
  *(f32x4*)(out + base) = o;
}

extern "C" void kernel_launch(void* const* d_in, const int* in_sizes, int n_in,
                              void* d_out, int out_size, void* d_ws, size_t ws_size,
                              hipStream_t stream) {
  const float* c     = (const float*)d_in[0];
  const float* e     = (const float*)d_in[1];
  const float* Wf    = (const float*)d_in[2];
  const float* bias  = (const float*)d_in[3];
  const float* gamma = (const float*)d_in[4];
  const float* beta  = (const float*)d_in[5];
  float* outp = (float*)d_out;

  char* ws = (char*)d_ws;
  const size_t TB = (size_t)32 * 1024 * 128 * 2;  // 8.39MB bf16 [bh][*][*] slot
  u16* eT  = (u16*)(ws);                 // S0: eT
  u16* cT  = (u16*)(ws + TB);            // S1: cT, later _eT
  u16* cV  = (u16*)(ws + 2 * TB);        // S2: cV; S2+S3 later x (f32, 16.8MB)
  u16* eV  = (u16*)(ws + 3 * TB);        // S3: eV
  u16* cT2 = (u16*)(ws + 4 * TB);        // S4: _cT
  u16* Wbf = (u16*)(ws + 5 * TB);        // 512KB
  float* chsum = (float*)(ws + 5 * TB + (1 << 20));
  float* chsq  = chsum + 512;
  float* scale = chsq + 512;
  float* shift = scale + 512;
  float* x     = (float*)(ws + 2 * TB);

  dim3 tb(256);
  dim3 pgrid(16, 4, 32);
  dim3 agrid(32, 8);   // (bh, tt): all tt of a bh-cluster share an XCD L2

  k_wcvt<<<dim3(128), tb, 0, stream>>>(Wf, Wbf);
  k_prep<<<pgrid, tb, 0, stream>>>(c, cV, cT);
  k_prep<<<pgrid, tb, 0, stream>>>(e, eV, eT);
  k_attn<<<agrid, dim3(512), 0, stream>>>(eT, cT, cV, cT2);   // _cT = attn(e,c,c)^T
  k_attn<<<agrid, dim3(512), 0, stream>>>(cT2, eT, eV, cT);   // _eT = attn(_c,e,e)^T
  hipMemsetAsync(chsum, 0, 2 * 512 * sizeof(float), stream);
  k_proj<<<dim3(64, 4), tb, 0, stream>>>(Wbf, cT, bias, x, chsum, chsq);
  k_stats<<<dim3(2), tb, 0, stream>>>(chsum, chsq, gamma, beta, scale, shift);
  k_final<<<dim3(4096), tb, 0, stream>>>(x, scale, shift, outp);
}

// Round 4
// 116.535 us; speedup vs baseline: 1.3188x; 1.0167x over previous
//
#include <hip/hip_runtime.h>
#include <hip/hip_bf16.h>

typedef __attribute__((ext_vector_type(8))) short short8;
typedef __attribute__((ext_vector_type(4))) float floatx4;
typedef __attribute__((ext_vector_type(4))) float f32x4;
typedef unsigned short u16;
typedef unsigned int u32;
typedef __attribute__((ext_vector_type(8))) unsigned short ushort8;

#define LSEQ 1024
#define CHD  128
#define QK_SCALE 0.08838834764831845f  // 1/sqrt(128)

static __device__ __forceinline__ u16 f2b(float f) {
  __hip_bfloat16 h = __float2bfloat16(f);
  return *reinterpret_cast<u16*>(&h);
}
static __device__ __forceinline__ u32 pack2(float a, float b) {
  return (u32)f2b(a) | ((u32)f2b(b) << 16);
}
static __device__ __forceinline__ void gl_lds16(const void* g, void* l) {
  __builtin_amdgcn_global_load_lds((__attribute__((address_space(1))) const void*)g,
                                   (__attribute__((address_space(3))) void*)l, 16, 0, 0);
}

// ---- prep: f32 [bh][128][1024] -> bf16 same layout (outV) + bf16 transposed (outT) ----
__global__ __launch_bounds__(256) void k_prep(const float* __restrict__ in,
                                              u16* __restrict__ outV,
                                              u16* __restrict__ outT) {
  __shared__ u16 tile[32][72];
  int bh = blockIdx.z, c0 = blockIdx.y * 32, s0 = blockIdx.x * 64;
  int tid = threadIdx.x;
  int cl = tid >> 3, sc = tid & 7;
  size_t off = ((size_t)bh * CHD + c0 + cl) * LSEQ + s0 + sc * 8;
  f32x4 a = *(const f32x4*)(in + off);
  f32x4 b = *(const f32x4*)(in + off + 4);
  ushort8 u;
#pragma unroll
  for (int j = 0; j < 4; ++j) { u[j] = f2b(a[j]); u[j + 4] = f2b(b[j]); }
  *(ushort8*)(outV + off) = u;
  *(ushort8*)&tile[cl][sc * 8] = u;
  __syncthreads();
  int sl = tid >> 2, cc = tid & 3;
  ushort8 v;
#pragma unroll
  for (int j = 0; j < 8; ++j) v[j] = tile[cc * 8 + j][sl];
  *(ushort8*)(outT + ((size_t)bh * LSEQ + s0 + sl) * CHD + c0 + cc * 8) = v;
}

// ---- W conv f32->bf16, plus zero the 4KB stats buffers (replaces 40us in-graph memset) ----
__global__ __launch_bounds__(256) void k_wcvt(const float* __restrict__ w, u16* __restrict__ wb,
                                              float* __restrict__ zbuf /* chsum||chsq, 1024 f32 */) {
  int tid = threadIdx.x;
  int base = (blockIdx.x * 256 + tid) * 8;
  f32x4 a = *(const f32x4*)(w + base);
  f32x4 b = *(const f32x4*)(w + base + 4);
  ushort8 u;
#pragma unroll
  for (int j = 0; j < 4; ++j) { u[j] = f2b(a[j]); u[j + 4] = f2b(b[j]); }
  *(ushort8*)(wb + base) = u;
  if (blockIdx.x == 0) {
    f32x4 z; z[0]=0.f; z[1]=0.f; z[2]=0.f; z[3]=0.f;
    *(f32x4*)(zbuf + tid * 4) = z;
  }
}

// ---- flash attention, 8 waves, t-tile 128, double-buffered 2-phase pipeline ----
__global__ __launch_bounds__(512) void k_attn(const u16* __restrict__ qT,
                                              const u16* __restrict__ kT,
                                              const u16* __restrict__ v,
                                              u16* __restrict__ outT) {
  __shared__ char ldsbuf[81920];  // K dbuf 2x16KB | V dbuf 2x16KB | P 8x2KB

  int bh = blockIdx.x, tt = blockIdx.y;
  int tid = threadIdx.x;
  int w = tid >> 6, lane = tid & 63;
  int lo = lane & 15, hi = lane >> 4;
  int t0 = tt * 128 + w * 16;

  const char* kTb = (const char*)(kT + (size_t)bh * LSEQ * CHD);  // row s: 256B
  const char* vb  = (const char*)(v  + (size_t)bh * CHD * LSEQ);  // row c: 2048B

  const u16* qbase = qT + ((size_t)bh * LSEQ + t0 + lo) * CHD + hi * 8;
  short8 bq[4];
#pragma unroll
  for (int ks = 0; ks < 4; ++ks) bq[ks] = *(const short8*)(qbase + ks * 32);

  floatx4 oacc[8];
#pragma unroll
  for (int i = 0; i < 8; ++i) { oacc[i][0]=0.f; oacc[i][1]=0.f; oacc[i][2]=0.f; oacc[i][3]=0.f; }
  float m_r = -1e30f, l_r = 0.f;

  char* pw = ldsbuf + 65536 + w * 2048 + lo * 128;
  int sw = (lo & 7) << 4;

  auto stageK = [&](int buf, int sb) {
    char* dst = ldsbuf + buf * 16384;
#pragma unroll
    for (int it = 0; it < 2; ++it) {
      int bb = it * 8192 + tid * 16;
      int row = bb >> 8;
      int cb = (bb & 255) ^ ((row & 7) << 4);
      gl_lds16(kTb + (size_t)(sb * 64 + row) * 256 + cb, dst + bb);
    }
  };
  auto stageV = [&](int buf, int sb) {
    char* dst = ldsbuf + 32768 + buf * 16384;
#pragma unroll
    for (int it = 0; it < 2; ++it) {
      int bb = it * 8192 + tid * 16;
      int row = bb >> 7;
      int cb = (bb & 127) ^ ((row & 7) << 4);
      gl_lds16(vb + (size_t)row * 2048 + sb * 128 + cb, dst + bb);
    }
  };

  stageK(0, 0); stageV(0, 0);
  __syncthreads();
  int cur = 0;

  for (int sb = 0; sb < 16; ++sb) {
    if (sb < 15) { stageK(cur ^ 1, sb + 1); stageV(cur ^ 1, sb + 1); }
    const char* ldsK = ldsbuf + cur * 16384;
    const char* ldsV = ldsbuf + 32768 + cur * 16384;

    // S^T = K.Q: lane holds S[s rows][t = t0+lo]
    float sa[4][4];
#pragma unroll
    for (int ss = 0; ss < 4; ++ss) {
      floatx4 acc; acc[0]=0.f; acc[1]=0.f; acc[2]=0.f; acc[3]=0.f;
      int row = ss * 16 + lo;
#pragma unroll
      for (int ks = 0; ks < 4; ++ks) {
        int cbyte = (ks * 64 + hi * 16) ^ ((row & 7) << 4);
        short8 a = *(const short8*)(ldsK + row * 256 + cbyte);
        acc = __builtin_amdgcn_mfma_f32_16x16x32_bf16(a, bq[ks], acc, 0, 0, 0);
      }
#pragma unroll
      for (int r = 0; r < 4; ++r) sa[ss][r] = acc[r] * QK_SCALE;
    }

    // online softmax over s for this t
    float bm = sa[0][0];
#pragma unroll
    for (int ss = 0; ss < 4; ++ss)
#pragma unroll
      for (int r = 0; r < 4; ++r) bm = fmaxf(bm, sa[ss][r]);
    bm = fmaxf(bm, __shfl_xor(bm, 16));
    bm = fmaxf(bm, __shfl_xor(bm, 32));
    float mn = fmaxf(m_r, bm);
    float corr = __expf(m_r - mn);
    m_r = mn;
    float rs = 0.f;
#pragma unroll
    for (int ss = 0; ss < 4; ++ss)
#pragma unroll
      for (int r = 0; r < 4; ++r) {
        float p = __expf(sa[ss][r] - mn);
        sa[ss][r] = p;
        rs += p;
      }
    rs += __shfl_xor(rs, 16);
    rs += __shfl_xor(rs, 32);
    l_r = l_r * corr + rs;
#pragma unroll
    for (int i = 0; i < 8; ++i) {
      oacc[i][0] *= corr; oacc[i][1] *= corr; oacc[i][2] *= corr; oacc[i][3] *= corr;
    }

    // P tile (bf16) -> per-wave LDS [t=lo][s], row-swizzled
#pragma unroll
    for (int ss = 0; ss < 4; ++ss)
#pragma unroll
      for (int r2 = 0; r2 < 2; ++r2) {
        int scol = ss * 16 + hi * 4 + r2 * 2;
        *(u32*)(pw + ((scol * 2) ^ sw)) = pack2(sa[ss][r2 * 2], sa[ss][r2 * 2 + 1]);
      }
    asm volatile("" ::: "memory");  // order P write -> P read (TBAA hazard)

    // PV: O[c][t] += sum_s V[c][s] P[t][s]
#pragma unroll
    for (int mt = 0; mt < 8; ++mt) {
      int crow = mt * 16 + lo;
      const char* va = ldsV + crow * 128;
      int vsw = (crow & 7) << 4;
#pragma unroll
      for (int k2 = 0; k2 < 2; ++k2) {
        short8 a = *(const short8*)(va + ((k2 * 64 + hi * 16) ^ vsw));
        short8 b = *(const short8*)(pw + ((k2 * 64 + hi * 16) ^ sw));
        oacc[mt] = __builtin_amdgcn_mfma_f32_16x16x32_bf16(a, b, oacc[mt], 0, 0, 0);
      }
    }
    __syncthreads();
    cur ^= 1;
  }

  // epilogue: transpose O via per-wave swizzled LDS tile, coalesced outT rows
  float inv = 1.0f / l_r;
  char* ot = ldsbuf + w * 4096;
#pragma unroll
  for (int mt = 0; mt < 8; ++mt)
#pragma unroll
    for (int r2 = 0; r2 < 2; ++r2) {
      int cb = (mt * 32 + hi * 8 + r2 * 4) ^ ((lo & 7) << 4);
      *(u32*)(ot + lo * 256 + cb) = pack2(oacc[mt][r2 * 2] * inv, oacc[mt][r2 * 2 + 1] * inv);
    }
  asm volatile("" ::: "memory");
  u16* orow = outT + ((size_t)bh * LSEQ + t0 + lo) * CHD;
#pragma unroll
  for (int it = 0; it < 4; ++it) {
    int cb = (it * 64 + hi * 16) ^ ((lo & 7) << 4);
    ushort8 d = *(const ushort8*)(ot + lo * 256 + cb);
    *(ushort8*)(orow + it * 32 + hi * 8) = d;
  }
}

// ---- proj GEMM 512(o) x 8192(b*l) x 512(c): 128x128 tile, BK=64, dbuf 2-phase ----
__global__ __launch_bounds__(256) void k_proj(const u16* __restrict__ Wm,    // bf16 [512][512]
                                              const u16* __restrict__ eT,    // bf16 [32][1024][128]
                                              const float* __restrict__ bias,
                                              float* __restrict__ x,         // f32 [8][512][1024]
                                              float* __restrict__ chsum,
                                              float* __restrict__ chsq) {
  __shared__ char lds[65536];  // A dbuf 2x16KB | B dbuf 2x16KB
  int lt = blockIdx.x, ot = blockIdx.y;
  int b = lt >> 3;
  int l0b = (lt & 7) * 128;
  int o0 = ot * 128;
  int tid = threadIdx.x, w = tid >> 6, lane = tid & 63, lo = lane & 15, hi = lane >> 4;
  int wm = w >> 1, wn = w & 1;
  const char* Wb = (const char*)Wm;
  const char* eTb = (const char*)eT;

  auto stageA = [&](int buf, int kb) {
    char* dst = lds + buf * 16384;
#pragma unroll
    for (int it = 0; it < 4; ++it) {
      int bb = it * 4096 + tid * 16;
      int row = bb >> 7;
      int cb = (bb & 127) ^ ((row & 7) << 4);
      gl_lds16(Wb + (size_t)(o0 + row) * 1024 + kb * 128 + cb, dst + bb);
    }
  };
  auto stageB = [&](int buf, int kb) {
    char* dst = lds + 32768 + buf * 16384;
    int page = b * 4 + (kb >> 1);
    int choff = (kb & 1) * 128;
#pragma unroll
    for (int it = 0; it < 4; ++it) {
      int bb = it * 4096 + tid * 16;
      int row = bb >> 7;
      int cb = (bb & 127) ^ ((row & 7) << 4);
      gl_lds16(eTb + ((size_t)page * 1024 + l0b + row) * 256 + choff + cb, dst + bb);
    }
  };

  floatx4 acc[4][4];
#pragma unroll
  for (int i = 0; i < 4; ++i)
#pragma unroll
    for (int j = 0; j < 4; ++j) { acc[i][j][0]=0.f; acc[i][j][1]=0.f; acc[i][j][2]=0.f; acc[i][j][3]=0.f; }

  stageA(0, 0); stageB(0, 0);
  __syncthreads();
  int cur = 0;

  for (int kb = 0; kb < 8; ++kb) {
    if (kb < 7) { stageA(cur ^ 1, kb + 1); stageB(cur ^ 1, kb + 1); }
    const char* A = lds + cur * 16384;
    const char* B = lds + 32768 + cur * 16384;
#pragma unroll
    for (int kk = 0; kk < 2; ++kk) {
      short8 af[4], bf[4];
#pragma unroll
      for (int mi = 0; mi < 4; ++mi) {
        int row = wm * 64 + mi * 16 + lo;
        af[mi] = *(const short8*)(A + row * 128 + ((kk * 64 + hi * 16) ^ ((row & 7) << 4)));
      }
#pragma unroll
      for (int ni = 0; ni < 4; ++ni) {
        int row = wn * 64 + ni * 16 + lo;
        bf[ni] = *(const short8*)(B + row * 128 + ((kk * 64 + hi * 16) ^ ((row & 7) << 4)));
      }
#pragma unroll
      for (int mi = 0; mi < 4; ++mi)
#pragma unroll
        for (int ni = 0; ni < 4; ++ni)
          acc[mi][ni] = __builtin_amdgcn_mfma_f32_16x16x32_bf16(af[mi], bf[ni], acc[mi][ni], 0, 0, 0);
    }
    __syncthreads();
    cur ^= 1;
  }

  // epilogue: bias + x write (f32) + per-channel partial stats
#pragma unroll
  for (int mi = 0; mi < 4; ++mi) {
#pragma unroll
    for (int r = 0; r < 4; ++r) {
      int o = o0 + wm * 64 + mi * 16 + hi * 4 + r;
      float bv = bias[o];
      float s = 0.f, q = 0.f;
#pragma unroll
      for (int ni = 0; ni < 4; ++ni) {
        float xv = acc[mi][ni][r] + bv;
        x[((size_t)b * 512 + o) * LSEQ + l0b + wn * 64 + ni * 16 + lo] = xv;
        s += xv; q += xv * xv;
      }
#pragma unroll
      for (int d = 1; d < 16; d <<= 1) { s += __shfl_xor(s, d); q += __shfl_xor(q, d); }
      if (lo == 0) {
        atomicAdd(&chsum[o], s);
        atomicAdd(&chsq[o], q);
      }
    }
  }
}

// ---- BN stats -> scale/shift ----
__global__ void k_stats(const float* __restrict__ chsum, const float* __restrict__ chsq,
                        const float* __restrict__ gamma, const float* __restrict__ beta,
                        float* __restrict__ scale, float* __restrict__ shift) {
  int ch = blockIdx.x * 256 + threadIdx.x;
  if (ch < 512) {
    const float invn = 1.0f / 8192.0f;
    float mean = chsum[ch] * invn;
    float var = chsq[ch] * invn - mean * mean;
    float rstd = rsqrtf(var + 1e-5f);
    float g = gamma[ch] * rstd;
    scale[ch] = g;
    shift[ch] = beta[ch] - mean * g;
  }
}

// ---- BN apply + swish: f32 in, f32 out ----
__global__ __launch_bounds__(256) void k_final(const float* __restrict__ x,
                                               const float* __restrict__ scale,
                                               const float* __restrict__ shift,
                                               float* __restrict__ out) {
  int idx = blockIdx.x * 256 + threadIdx.x;
  int base = idx * 4;
  int ch = (base >> 10) & 511;
  float sc = scale[ch], sh = shift[ch];
  f32x4 vx = *(const f32x4*)(x + base);
  f32x4 o;
#pragma unroll
  for (int j = 0; j < 4; ++j) {
    float xn = vx[j] * sc + sh;
    float sg = 1.0f / (1.0f + __expf(-xn));
    o[j] = xn * sg;
  }
  *(f32x4*)(out + base) = o;
}

extern "C" void kernel_launch(void* const* d_in, const int* in_sizes, int n_in,
                              void* d_out, int out_size, void* d_ws, size_t ws_size,
                              hipStream_t stream) {
  const float* c     = (const float*)d_in[0];
  const float* e     = (const float*)d_in[1];
  const float* Wf    = (const float*)d_in[2];
  const float* bias  = (const float*)d_in[3];
  const float* gamma = (const float*)d_in[4];
  const float* beta  = (const float*)d_in[5];
  float* outp = (float*)d_out;

  char* ws = (char*)d_ws;
  const size_t TB = (size_t)32 * 1024 * 128 * 2;  // 8.39MB bf16 [bh][*][*] slot
  u16* eT  = (u16*)(ws);                 // S0: eT
  u16* cT  = (u16*)(ws + TB);            // S1: cT, later _eT
  u16* cV  = (u16*)(ws + 2 * TB);        // S2: cV; S2+S3 later x (f32, 16.8MB)
  u16* eV  = (u16*)(ws + 3 * TB);        // S3: eV
  u16* cT2 = (u16*)(ws + 4 * TB);        // S4: _cT
  u16* Wbf = (u16*)(ws + 5 * TB);        // 512KB
  float* chsum = (float*)(ws + 5 * TB + (1 << 20));
  float* chsq  = chsum + 512;
  float* scale = chsq + 512;
  float* shift = scale + 512;
  float* x     = (float*)(ws + 2 * TB);

  dim3 tb(256);
  dim3 pgrid(16, 4, 32);
  dim3 agrid(32, 8);   // (bh, tt): all tt of a bh-cluster share an XCD L2

  k_wcvt<<<dim3(128), tb, 0, stream>>>(Wf, Wbf, chsum);  // also zeroes chsum||chsq (4KB)
  k_prep<<<pgrid, tb, 0, stream>>>(c, cV, cT);
  k_prep<<<pgrid, tb, 0, stream>>>(e, eV, eT);
  k_attn<<<agrid, dim3(512), 0, stream>>>(eT, cT, cV, cT2);   // _cT = attn(e,c,c)^T
  k_attn<<<agrid, dim3(512), 0, stream>>>(cT2, eT, eV, cT);   // _eT = attn(_c,e,e)^T
  k_proj<<<dim3(64, 4), tb, 0, stream>>>(Wbf, cT, bias, x, chsum, chsq);
  k_stats<<<dim3(2), tb, 0, stream>>>(chsum, chsq, gamma, beta, scale, shift);
  k_final<<<dim3(4096), tb, 0, stream>>>(x, scale, shift, outp);
}